// Round 9
// baseline (113.911 us; speedup 1.0000x reference)
//
#include <hip/hip_runtime.h>
#include <hip/hip_bf16.h>
#include <stdint.h>

// Problem constants (from reference): B=32, NB=64, PL=20, FD=4096, H=1024
#define B_   32
#define NB_  64
#define PL_  20
#define FD_  4096
#define H_   1024
#define M_   (B_ * NB_)   // 2048 regions

typedef short bf16x8 __attribute__((ext_vector_type(8)));
typedef float f32x4  __attribute__((ext_vector_type(4)));

// f32 -> bf16 round-to-nearest-even
__device__ __forceinline__ ushort f2bf(float f) {
    uint32_t u = __builtin_bit_cast(uint32_t, f);
    u += 0x7fffu + ((u >> 16) & 1u);
    return (ushort)(u >> 16);
}

// ---------------------------------------------------------------------------
// Fused prep kernel (block-range dispatch) — unchanged from R8 (verified).
//   blocks [0, 2048)          : pool language -> pooled bf16 (1 region/block)
//   blocks [2048, 10240)      : vision f32 -> bf16 (1024 elems/block)
//   blocks [10240, 14336)     : WvT[n][k] = bf16(Wv[k][n])  (32x32 tiles)
//   blocks [14336, 15360)     : WlT[n][k] = bf16(Wl[k][n])
// ---------------------------------------------------------------------------
__global__ __launch_bounds__(256) void prep_kernel(
    const float* __restrict__ lang, const int* __restrict__ plen,
    ushort* __restrict__ pooled,
    const float* __restrict__ vision, ushort* __restrict__ visionb,
    const float* __restrict__ Wv, ushort* __restrict__ WvT,
    const float* __restrict__ Wl, ushort* __restrict__ WlT)
{
    __shared__ float tile[32][33];   // transpose staging (+1 pad)
    int blk = blockIdx.x;
    int tid = threadIdx.x;

    if (blk < M_) {
        // ---- pool: region r = blk, thread covers 4 h's ----
        int r = blk;
        int h = tid << 2;
        const float* base = lang + (size_t)r * (PL_ * H_) + h;
        float sx = 0.f, sy = 0.f, sz = 0.f, sw = 0.f;
#pragma unroll
        for (int p = 0; p < PL_; ++p) {
            float4 v = *(const float4*)(base + (size_t)p * H_);
            sx += v.x; sy += v.y; sz += v.z; sw += v.w;
        }
        float inv = 1.0f / (float)plen[r];
        ushort4 o = make_ushort4(f2bf(sx * inv), f2bf(sy * inv),
                                 f2bf(sz * inv), f2bf(sw * inv));
        *(ushort4*)(pooled + (size_t)r * H_ + h) = o;
    } else if (blk < M_ + 8192) {
        // ---- vision f32 -> bf16, x4 vectorized ----
        int i = (blk - M_) * 256 + tid;        // i < 2048*4096/4
        float4 v = ((const float4*)vision)[i];
        ushort4 o = make_ushort4(f2bf(v.x), f2bf(v.y), f2bf(v.z), f2bf(v.w));
        ((ushort4*)visionb)[i] = o;
    } else {
        const float* W; ushort* Wt; int K, b;
        if (blk < M_ + 8192 + 4096) { W = Wv; Wt = WvT; K = FD_; b = blk - (M_ + 8192); }
        else                        { W = Wl; Wt = WlT; K = H_;  b = blk - (M_ + 8192 + 4096); }
        int n0 = (b & 31) * 32, k0 = (b >> 5) * 32;
        int tx = tid & 31, ty = tid >> 5;      // ty in 0..7
#pragma unroll
        for (int i = 0; i < 32; i += 8)
            tile[ty + i][tx] = W[(size_t)(k0 + ty + i) * H_ + n0 + tx];
        __syncthreads();
#pragma unroll
        for (int i = 0; i < 32; i += 8)
            Wt[(size_t)(n0 + ty + i) * K + k0 + tx] = f2bf(tile[tx][ty + i]);
    }
}

// ---------------------------------------------------------------------------
// Dual bf16 GEMM-BT, depth-3 counted-vmcnt (T4) + swizzle (T2), acc[4][4]:
//   C[M][N] = A[M][K] * Bt[N][K]^T + bias
// 1D grid, 256 blocks x 256 threads (4 waves, 2x2), per-wave 64x64 = acc[4][4]
//   -> 16 ds_read_b128 per 32 MFMA per K-step (0.5 reads/MFMA, m97 shape);
//   per-CU LDS read load drops 98KB -> 64KB per K-step vs R8.
//   wgid [0,128)  : vision GEMM (K=4096)  — tile x = wgid>>3, y = wgid&7
//   wgid [128,256): language GEMM (K=1024)
// XCD pinning: XCD == y (round-robin) -> B-panel (1 MB) L2-resident per XCD.
// 4 LDS buffers (128 KB). Stage = 8 gload_lds issues (A j0..3, B j0..3).
// Main loop: s_waitcnt vmcnt(16) -> s_barrier -> stage(kt+3) -> compute(kt).
// Tail peeled with vmcnt 16 -> 8 -> 0 (compile-time immediates).
// Swizzle (rule 21): linear LDS dest, source col = cbl ^ ((row&7)<<4),
// reads apply the same XOR -> uniform bank spread on ds_read_b128.
// ---------------------------------------------------------------------------
#define BM 128
#define BN 128
#define BK 64
#define NBUF 4

__device__ __forceinline__ void async16(const void* g, void* l) {
    __builtin_amdgcn_global_load_lds(
        (const __attribute__((address_space(1))) void*)g,
        (__attribute__((address_space(3))) void*)l, 16, 0, 0);
}

// Stage one 128x64 A-tile (16 KB) + 128x64 B-tile (16 KB), bf16.
// 256 threads x 16B x 4 issues per matrix. LDS linear; source pre-swizzled.
__device__ __forceinline__ void stage_tile(
    const char* Ag, const char* Bg, size_t Kb, size_t ko,
    char* AsB, char* BsB, int tid)
{
#pragma unroll
    for (int j = 0; j < 4; ++j) {
        int off = j * 4096 + tid * 16;                  // linear LDS byte off
        int row = off >> 7;                             // 128 B per row
        int cbl = off & 127;                            // LDS byte col
        int cbg = cbl ^ ((row & 7) << 4);               // swizzled global col
        async16(Ag + (size_t)row * Kb + ko + cbg, AsB + off);
        async16(Bg + (size_t)row * Kb + ko + cbg, BsB + off);
    }
}

__global__ __launch_bounds__(256) void gemm_bt_dual(
    const ushort* __restrict__ A1, const ushort* __restrict__ Bt1,
    const float* __restrict__ bias1, float* __restrict__ C1,
    const ushort* __restrict__ A2, const ushort* __restrict__ Bt2,
    const float* __restrict__ bias2, float* __restrict__ C2)
{
    __shared__ ushort As[NBUF][BM * BK];   // 4 x 16 KB
    __shared__ ushort Bs[NBUF][BN * BK];   // 4 x 16 KB

    int wg = blockIdx.x;
    bool isV = wg < 128;
    int w = isV ? wg : wg - 128;
    int y = w & 7, x = w >> 3;          // XCD == y (round-robin dispatch)

    const ushort* A  = isV ? A1 : A2;
    const ushort* Bt = isV ? Bt1 : Bt2;
    const float* bias = isV ? bias1 : bias2;
    float* C = isV ? C1 : C2;
    int K = isV ? FD_ : H_;

    const int N = H_;
    int tid  = threadIdx.x;
    int wave = tid >> 6, lane = tid & 63;
    int lx = lane & 15, lz = lane >> 4;
    int wr = wave >> 1, wc = wave & 1;  // 2x2 waves, each owns 64x64
    int row0 = x * BM;
    int col0 = y * BN;

    size_t Kb = (size_t)K * 2;          // bytes per logical row

    const char* Ag = (const char*)A  + (size_t)row0 * Kb;
    const char* Bg = (const char*)Bt + (size_t)col0 * Kb;

    int sw = (lx & 7) << 4;             // read-side swizzle XOR

    f32x4 acc[4][4] = {};

    int nk = K >> 6;                    // K-steps of 64 (vision 64, lang 16)

    // prologue: stage 3 tiles (24 outstanding loads per thread)
    stage_tile(Ag, Bg, Kb, 0,   (char*)As[0], (char*)Bs[0], tid);
    stage_tile(Ag, Bg, Kb, 128, (char*)As[1], (char*)Bs[1], tid);
    stage_tile(Ag, Bg, Kb, 256, (char*)As[2], (char*)Bs[2], tid);

#define COMPUTE_TILE(BUF)                                                     \
    {                                                                         \
        const char* Ab = (const char*)As[(BUF)];                              \
        const char* Bb = (const char*)Bs[(BUF)];                              \
        bf16x8 af[2][4], bfr[2][4];                                           \
        _Pragma("unroll")                                                     \
        for (int kk = 0; kk < 2; ++kk) {                                      \
            _Pragma("unroll")                                                 \
            for (int m = 0; m < 4; ++m)                                       \
                af[kk][m] = *(const bf16x8*)(Ab +                             \
                    (wr * 64 + m * 16 + lx) * 128 +                           \
                    ((kk * 64 + lz * 16) ^ sw));                              \
            _Pragma("unroll")                                                 \
            for (int n = 0; n < 4; ++n)                                       \
                bfr[kk][n] = *(const bf16x8*)(Bb +                            \
                    (wc * 64 + n * 16 + lx) * 128 +                           \
                    ((kk * 64 + lz * 16) ^ sw));                              \
        }                                                                     \
        _Pragma("unroll")                                                     \
        for (int kk = 0; kk < 2; ++kk)                                        \
            _Pragma("unroll")                                                 \
            for (int m = 0; m < 4; ++m)                                       \
                _Pragma("unroll")                                             \
                for (int n = 0; n < 4; ++n)                                   \
                    acc[m][n] = __builtin_amdgcn_mfma_f32_16x16x32_bf16(      \
                        af[kk][m], bfr[kk][n], acc[m][n], 0, 0, 0);           \
    }

    for (int kt = 0; kt < nk - 3; ++kt) {
        // tile kt's 8 loads done; leave tiles kt+1, kt+2 (16) in flight
        asm volatile("s_waitcnt vmcnt(16)" ::: "memory");
        __builtin_amdgcn_s_barrier();   // all waves' stage(kt) visible;
                                        // compute(kt-1) done -> buf reusable
        stage_tile(Ag, Bg, Kb, (size_t)(kt + 3) * 128,
                   (char*)As[(kt + 3) & 3], (char*)Bs[(kt + 3) & 3], tid);
        COMPUTE_TILE(kt & 3);
    }
    // peeled tail: drain 16 -> 8 -> 0
    asm volatile("s_waitcnt vmcnt(16)" ::: "memory");
    __builtin_amdgcn_s_barrier();
    COMPUTE_TILE((nk - 3) & 3);
    asm volatile("s_waitcnt vmcnt(8)" ::: "memory");
    __builtin_amdgcn_s_barrier();
    COMPUTE_TILE((nk - 2) & 3);
    asm volatile("s_waitcnt vmcnt(0)" ::: "memory");
    __builtin_amdgcn_s_barrier();
    COMPUTE_TILE((nk - 1) & 3);

    // Epilogue. D frag: col = lane&15, row = (lane>>4)*4 + reg  [verified map]
#pragma unroll
    for (int m = 0; m < 4; ++m) {
        int row = row0 + wr * 64 + m * 16 + lz * 4;
#pragma unroll
        for (int n = 0; n < 4; ++n) {
            int col = col0 + wc * 64 + n * 16 + lx;
            float bb = bias[col];
#pragma unroll
            for (int r = 0; r < 4; ++r)
                C[(size_t)(row + r) * N + col] = acc[m][n][r] + bb;
        }
    }
#undef COMPUTE_TILE
}

// ---------------------------------------------------------------------------
extern "C" void kernel_launch(void* const* d_in, const int* in_sizes, int n_in,
                              void* d_out, int out_size, void* d_ws, size_t ws_size,
                              hipStream_t stream) {
    const float* vision   = (const float*)d_in[0];   // [2048, 4096]
    const float* language = (const float*)d_in[1];   // [2048, 20, 1024]
    const int*   plen     = (const int*)d_in[2];     // [2048]
    const float* Wv       = (const float*)d_in[3];   // [4096, 1024]
    const float* bv       = (const float*)d_in[4];   // [1024]
    const float* Wl       = (const float*)d_in[5];   // [1024, 1024]
    const float* bl       = (const float*)d_in[6];   // [1024]

    float* out      = (float*)d_out;
    float* lang_map = out;                        // output 0: [2048,1024]
    float* vis_map  = out + (size_t)M_ * H_;      // output 1: [2048,1024]

    char* ws = (char*)d_ws;
    ushort* pooled  = (ushort*)(ws);                   // 4 MB  [2048][1024]
    ushort* visionb = (ushort*)(ws + (4u  << 20));     // 16 MB [2048][4096]
    ushort* WvT     = (ushort*)(ws + (20u << 20));     // 8 MB  [1024][4096]
    ushort* WlT     = (ushort*)(ws + (28u << 20));     // 2 MB  [1024][1024]

    // prep: 2048 pool + 8192 convert + 4096 WvT + 1024 WlT = 15360 blocks
    hipLaunchKernelGGL(prep_kernel, dim3(15360), dim3(256), 0, stream,
                       language, plen, pooled, vision, visionb,
                       Wv, WvT, Wl, WlT);
    // GEMM: 256 blocks x 256 threads (128 vision + 128 language tiles)
    hipLaunchKernelGGL(gemm_bt_dual, dim3(256), dim3(256), 0, stream,
                       visionb, WvT, bv, vis_map,
                       pooled,  WlT, bl, lang_map);
}

// Round 10
// 91.434 us; speedup vs baseline: 1.2458x; 1.2458x over previous
//
#include <hip/hip_runtime.h>
#include <hip/hip_bf16.h>
#include <stdint.h>

// Problem constants (from reference): B=32, NB=64, PL=20, FD=4096, H=1024
#define B_   32
#define NB_  64
#define PL_  20
#define FD_  4096
#define H_   1024
#define M_   (B_ * NB_)   // 2048 regions

typedef short bf16x8 __attribute__((ext_vector_type(8)));
typedef float f32x4  __attribute__((ext_vector_type(4)));

// f32 -> bf16 round-to-nearest-even
__device__ __forceinline__ ushort f2bf(float f) {
    uint32_t u = __builtin_bit_cast(uint32_t, f);
    u += 0x7fffu + ((u >> 16) & 1u);
    return (ushort)(u >> 16);
}

// ---------------------------------------------------------------------------
// Fused prep kernel (block-range dispatch) — unchanged (verified R4-R9).
// ---------------------------------------------------------------------------
__global__ __launch_bounds__(256) void prep_kernel(
    const float* __restrict__ lang, const int* __restrict__ plen,
    ushort* __restrict__ pooled,
    const float* __restrict__ vision, ushort* __restrict__ visionb,
    const float* __restrict__ Wv, ushort* __restrict__ WvT,
    const float* __restrict__ Wl, ushort* __restrict__ WlT)
{
    __shared__ float tile[32][33];   // transpose staging (+1 pad)
    int blk = blockIdx.x;
    int tid = threadIdx.x;

    if (blk < M_) {
        int r = blk;
        int h = tid << 2;
        const float* base = lang + (size_t)r * (PL_ * H_) + h;
        float sx = 0.f, sy = 0.f, sz = 0.f, sw = 0.f;
#pragma unroll
        for (int p = 0; p < PL_; ++p) {
            float4 v = *(const float4*)(base + (size_t)p * H_);
            sx += v.x; sy += v.y; sz += v.z; sw += v.w;
        }
        float inv = 1.0f / (float)plen[r];
        ushort4 o = make_ushort4(f2bf(sx * inv), f2bf(sy * inv),
                                 f2bf(sz * inv), f2bf(sw * inv));
        *(ushort4*)(pooled + (size_t)r * H_ + h) = o;
    } else if (blk < M_ + 8192) {
        int i = (blk - M_) * 256 + tid;        // i < 2048*4096/4
        float4 v = ((const float4*)vision)[i];
        ushort4 o = make_ushort4(f2bf(v.x), f2bf(v.y), f2bf(v.z), f2bf(v.w));
        ((ushort4*)visionb)[i] = o;
    } else {
        const float* W; ushort* Wt; int K, b;
        if (blk < M_ + 8192 + 4096) { W = Wv; Wt = WvT; K = FD_; b = blk - (M_ + 8192); }
        else                        { W = Wl; Wt = WlT; K = H_;  b = blk - (M_ + 8192 + 4096); }
        int n0 = (b & 31) * 32, k0 = (b >> 5) * 32;
        int tx = tid & 31, ty = tid >> 5;      // ty in 0..7
#pragma unroll
        for (int i = 0; i < 32; i += 8)
            tile[ty + i][tx] = W[(size_t)(k0 + ty + i) * H_ + n0 + tx];
        __syncthreads();
#pragma unroll
        for (int i = 0; i < 32; i += 8)
            Wt[(size_t)(n0 + ty + i) * K + k0 + tx] = f2bf(tile[tx][ty + i]);
    }
}

// ---------------------------------------------------------------------------
// Dual bf16 GEMM-BT, split-K vision, 2 blocks/CU, counted vmcnt + T2 swizzle:
//   C[M][N] = A[M][K] * Bt[N][K]^T (+ bias)
// Grid: 512 blocks x 256 threads (4 waves 2x2, per-wave 64x64 = acc[4][4]).
//   wgid [0,384)  : vision GEMM (K=4096) split-K 3-way: ks = wg/128,
//                   K-steps {22,21,21}; partials via atomicAdd (C pre-zeroed);
//                   bias added by split ks==0.
//   wgid [384,512): language GEMM (K=1024, 16 steps), plain stores + bias.
// All blocks ~16-22 K-steps -> balanced; 2 blocks/CU -> 8 waves/CU (the
// R4-proven occupancy) with cross-block async overlap of barriers.
// LDS: NBUF=2 x (16KB A + 16KB B) = 64 KB -> two blocks co-resident.
// Pipeline (depth-2 counted vmcnt, FIFO: vmcnt(8) == "tile kt landed"):
//   prologue stage(0), stage(1)    [16 outstanding/thread, 8 per tile]
//   iter kt: vmcnt(kt<nk-1 ? 8:0); barrier; ds_read frags(kt); lgkmcnt(0);
//            barrier; if(kt+2<nk) stage(kt+2); MFMA(kt)
// Swizzle (rule 21): linear LDS dest, global source col ^= ((row&7)<<4),
// read col applies the same XOR (verified R8/R9).
// XCD pinning: wg%8 == y for all ranges -> B-panel L2-resident per XCD.
// ---------------------------------------------------------------------------
#define BM 128
#define BN 128
#define BK 64

__device__ __forceinline__ void async16(const void* g, void* l) {
    __builtin_amdgcn_global_load_lds(
        (const __attribute__((address_space(1))) void*)g,
        (__attribute__((address_space(3))) void*)l, 16, 0, 0);
}

// Stage one 128x64 A-tile (16 KB) + 128x64 B-tile (16 KB), bf16.
// 256 threads x 16B x 4 issues per matrix (8 loads/thread/tile).
__device__ __forceinline__ void stage_tile(
    const char* Ag, const char* Bg, size_t Kb, size_t ko,
    char* AsB, char* BsB, int tid)
{
#pragma unroll
    for (int j = 0; j < 4; ++j) {
        int off = j * 4096 + tid * 16;                  // linear LDS byte off
        int row = off >> 7;                             // 128 B per row
        int cbl = off & 127;                            // LDS byte col
        int cbg = cbl ^ ((row & 7) << 4);               // swizzled global col
        async16(Ag + (size_t)row * Kb + ko + cbg, AsB + off);
        async16(Bg + (size_t)row * Kb + ko + cbg, BsB + off);
    }
}

__global__ __launch_bounds__(256) void gemm_bt_dual(
    const ushort* __restrict__ A1, const ushort* __restrict__ Bt1,
    const float* __restrict__ bias1, float* __restrict__ C1,
    const ushort* __restrict__ A2, const ushort* __restrict__ Bt2,
    const float* __restrict__ bias2, float* __restrict__ C2)
{
    __shared__ ushort As[2][BM * BK];   // 2 x 16 KB
    __shared__ ushort Bs[2][BN * BK];   // 2 x 16 KB

    int wg = blockIdx.x;
    bool isV = wg < 384;
    int w, ks, nk, k0s;
    if (isV) {
        ks = wg >> 7;                   // 0..2
        w  = wg & 127;
        nk  = (ks == 0) ? 22 : 21;      // 22+21+21 = 64 K-steps
        k0s = (ks == 0) ? 0 : (22 + (ks - 1) * 21);
    } else {
        ks = 0; w = wg - 384; nk = 16; k0s = 0;
    }
    int y = w & 7, x = w >> 3;          // XCD == wg%8 == y (round-robin)

    const ushort* A   = isV ? A1 : A2;
    const ushort* Bt  = isV ? Bt1 : Bt2;
    const float* bias = isV ? bias1 : bias2;
    float* C          = isV ? C1 : C2;
    int K             = isV ? FD_ : H_;

    const int N = H_;
    int tid  = threadIdx.x;
    int wave = tid >> 6, lane = tid & 63;
    int lx = lane & 15, lz = lane >> 4;
    int wr = wave >> 1, wc = wave & 1;  // 2x2 waves, each owns 64x64
    int row0 = x * BM;
    int col0 = y * BN;

    size_t Kb = (size_t)K * 2;          // bytes per logical row

    const char* Ag = (const char*)A  + (size_t)row0 * Kb;
    const char* Bg = (const char*)Bt + (size_t)col0 * Kb;

    int sw = (lx & 7) << 4;             // read-side swizzle XOR

    f32x4 acc[4][4] = {};

    // prologue: stage tiles 0,1 (16 outstanding loads per thread)
    stage_tile(Ag, Bg, Kb, (size_t)k0s * 128,       (char*)As[0], (char*)Bs[0], tid);
    stage_tile(Ag, Bg, Kb, (size_t)(k0s + 1) * 128, (char*)As[1], (char*)Bs[1], tid);

    for (int kt = 0; kt < nk; ++kt) {
        if (kt < nk - 1) asm volatile("s_waitcnt vmcnt(8)" ::: "memory");
        else             asm volatile("s_waitcnt vmcnt(0)" ::: "memory");
        __builtin_amdgcn_s_barrier();   // all waves' stage(kt) visible

        const char* Ab = (const char*)As[kt & 1];
        const char* Bb = (const char*)Bs[kt & 1];
        bf16x8 af[2][4], bfr[2][4];
#pragma unroll
        for (int kk = 0; kk < 2; ++kk) {
#pragma unroll
            for (int m = 0; m < 4; ++m)
                af[kk][m] = *(const bf16x8*)(Ab +
                    (wr * 64 + m * 16 + lx) * 128 + ((kk * 64 + lz * 16) ^ sw));
#pragma unroll
            for (int n = 0; n < 4; ++n)
                bfr[kk][n] = *(const bf16x8*)(Bb +
                    (wc * 64 + n * 16 + lx) * 128 + ((kk * 64 + lz * 16) ^ sw));
        }
        asm volatile("s_waitcnt lgkmcnt(0)" ::: "memory"); // reads complete
        __builtin_amdgcn_s_barrier();   // buffer kt now reusable block-wide

        if (kt + 2 < nk)
            stage_tile(Ag, Bg, Kb, (size_t)(k0s + kt + 2) * 128,
                       (char*)As[kt & 1], (char*)Bs[kt & 1], tid);

#pragma unroll
        for (int kk = 0; kk < 2; ++kk)
#pragma unroll
            for (int m = 0; m < 4; ++m)
#pragma unroll
                for (int n = 0; n < 4; ++n)
                    acc[m][n] = __builtin_amdgcn_mfma_f32_16x16x32_bf16(
                        af[kk][m], bfr[kk][n], acc[m][n], 0, 0, 0);
    }

    // Epilogue. D frag: col = lane&15, row = (lane>>4)*4 + reg  [verified map]
#pragma unroll
    for (int m = 0; m < 4; ++m) {
        int row = row0 + wr * 64 + m * 16 + lz * 4;
#pragma unroll
        for (int n = 0; n < 4; ++n) {
            int col = col0 + wc * 64 + n * 16 + lx;
            float bb = (ks == 0) ? bias[col] : 0.f;
            if (isV) {
#pragma unroll
                for (int r = 0; r < 4; ++r)
                    atomicAdd(&C[(size_t)(row + r) * N + col],
                              acc[m][n][r] + bb);
            } else {
#pragma unroll
                for (int r = 0; r < 4; ++r)
                    C[(size_t)(row + r) * N + col] = acc[m][n][r] + bb;
            }
        }
    }
}

// ---------------------------------------------------------------------------
extern "C" void kernel_launch(void* const* d_in, const int* in_sizes, int n_in,
                              void* d_out, int out_size, void* d_ws, size_t ws_size,
                              hipStream_t stream) {
    const float* vision   = (const float*)d_in[0];   // [2048, 4096]
    const float* language = (const float*)d_in[1];   // [2048, 20, 1024]
    const int*   plen     = (const int*)d_in[2];     // [2048]
    const float* Wv       = (const float*)d_in[3];   // [4096, 1024]
    const float* bv       = (const float*)d_in[4];   // [1024]
    const float* Wl       = (const float*)d_in[5];   // [1024, 1024]
    const float* bl       = (const float*)d_in[6];   // [1024]

    float* out      = (float*)d_out;
    float* lang_map = out;                        // output 0: [2048,1024]
    float* vis_map  = out + (size_t)M_ * H_;      // output 1: [2048,1024]

    char* ws = (char*)d_ws;
    ushort* pooled  = (ushort*)(ws);                   // 4 MB  [2048][1024]
    ushort* visionb = (ushort*)(ws + (4u  << 20));     // 16 MB [2048][4096]
    ushort* WvT     = (ushort*)(ws + (20u << 20));     // 8 MB  [1024][4096]
    ushort* WlT     = (ushort*)(ws + (28u << 20));     // 2 MB  [1024][1024]

    // vision output accumulated via atomics -> zero it every launch
    // (replay-safe: each replay re-zeroes before accumulating)
    hipMemsetAsync(vis_map, 0, (size_t)M_ * H_ * sizeof(float), stream);

    // prep: 2048 pool + 8192 convert + 4096 WvT + 1024 WlT = 15360 blocks
    hipLaunchKernelGGL(prep_kernel, dim3(15360), dim3(256), 0, stream,
                       language, plen, pooled, vision, visionb,
                       Wv, WvT, Wl, WlT);
    // GEMM: 512 blocks x 256 threads (384 vision split-K + 128 language)
    hipLaunchKernelGGL(gemm_bt_dual, dim3(512), dim3(256), 0, stream,
                       visionb, WvT, bv, vis_map,
                       pooled,  WlT, bl, lang_map);
}